// Round 5
// baseline (48.643 us; speedup 1.0000x reference)
//
#include <hip/hip_runtime.h>

#define NPTS  8192
#define DIM   512
#define NK    64
#define TM    64            // rows per tile
#define NTILE (NPTS/TM)     // 128
#define KH    256           // dims per K-half (per gemm block)
#define CH    128           // dims per staged chunk
#define APITCH 33           // A LDS pitch in float4 units (32+1 pad)

// workspace layout (float offsets)
#define WS_CTT   0                              // [512][64]      = 32768
#define WS_SQC   (DIM*NK)                       // [64]
#define WS_SC    (WS_SQC + NK)                  // [64]
#define WS_STATP (WS_SC + NK)                   // [128][2][64] float2 = 32768 f
#define WS_DOTP  (WS_STATP + NTILE*2*TM*2)      // [128][2][64][64]   = 1048576 f

// ---------------------------------------------------------------------------
// Prep: gather centroid rows into transposed ctT[d][n], per-centroid stats,
// and zero the energy accumulator (replaces a costly memset dispatch).
// ---------------------------------------------------------------------------
__global__ __launch_bounds__(64) void prep_kernel(
    const float* __restrict__ f, const int* __restrict__ cid,
    float* __restrict__ ws, float* __restrict__ out)
{
    const int k = blockIdx.x;      // one wave per centroid
    const int lane = threadIdx.x;
    if (k == 0 && lane == 0) out[0] = 0.f;
    float* ctT = ws + WS_CTT;
    const float* row = f + (size_t)cid[k] * DIM;
    float4 a = *(const float4*)(row + lane * 8);
    float4 b = *(const float4*)(row + lane * 8 + 4);
    const int d = lane * 8;
    ctT[(d+0)*NK + k] = a.x;  ctT[(d+1)*NK + k] = a.y;
    ctT[(d+2)*NK + k] = a.z;  ctT[(d+3)*NK + k] = a.w;
    ctT[(d+4)*NK + k] = b.x;  ctT[(d+5)*NK + k] = b.y;
    ctT[(d+6)*NK + k] = b.z;  ctT[(d+7)*NK + k] = b.w;
    float s = a.x+a.y+a.z+a.w + b.x+b.y+b.z+b.w;
    float q = a.x*a.x+a.y*a.y+a.z*a.z+a.w*a.w
            + b.x*b.x+b.y*b.y+b.z*b.z+b.w*b.w;
    #pragma unroll
    for (int off = 32; off; off >>= 1) {
        s += __shfl_xor(s, off);
        q += __shfl_xor(q, off);
    }
    if (lane == 0) { ws[WS_SQC + k] = q; ws[WS_SC + k] = s; }
}

// ---------------------------------------------------------------------------
// GEMM: 256 blocks (128 tiles x 2 K-halves) x 512 threads. lane=row (64 rows),
// each lane accumulates ALL 64 columns -> B reads are wave-uniform (LDS
// broadcast, ~free). 8 waves split the 256-dim K-half (32 dims each); chunked
// staging (128 dims) with register prefetch; LDS tree combines wave partials.
// Per lane LDS data traffic: 1 b128 per 4 dims per 256 FMAs (0.06 B/FMA).
// ---------------------------------------------------------------------------
__global__ __launch_bounds__(512, 2) void gemm_kernel(
    const float* __restrict__ f, const float* __restrict__ ctT,
    float* __restrict__ ws)
{
    __shared__ union {
        struct {
            float4 A[TM * APITCH];   // [64][33] f4  (33.8 KB)
            float4 B[CH * 16];       // [128][16] f4 (32 KB)
        } st;
        float4 comb[4 * TM * 17];    // [w][64][17] f4 (69.6 KB), padded
    } u;
    __shared__ float2 statLDS[8][TM];  // 4 KB

    const int t     = threadIdx.x;
    const int lane  = t & 63;          // = row within tile
    const int wave  = t >> 6;          // = K-slice (16 dims per chunk)
    const int tile  = blockIdx.x & (NTILE - 1);
    const int khalf = blockIdx.x >> 7; // blocks b and b+128 share a tile/XCD
    const int kbase = khalf * KH;

    const float* fA = f   + (size_t)(tile * TM) * DIM + kbase;
    const float* fB = ctT + (size_t)kbase * NK;

    float acc[NK];
    #pragma unroll
    for (int i = 0; i < NK; ++i) acc[i] = 0.f;
    float ssum = 0.f, qsum = 0.f;

    // ---- stage chunk 0 (coalesced; A row-padded 2-way-free, B linear)
    #pragma unroll
    for (int r = 0; r < 4; ++r) {
        int i = t + 512 * r;
        int ar = i >> 5, ac = i & 31;
        u.st.A[ar * APITCH + ac] = *(const float4*)(fA + (size_t)ar * DIM + ac * 4);
        int br = i >> 4, bc = i & 15;
        u.st.B[br * 16 + bc] = *(const float4*)(fB + (size_t)br * NK + bc * 4);
    }
    __syncthreads();

    // ---- prefetch chunk 1 into registers (T14: issue early, write late)
    float4 hA[4], hB[4];
    #pragma unroll
    for (int r = 0; r < 4; ++r) {
        int i = t + 512 * r;
        int ar = i >> 5, ac = i & 31;
        hA[r] = *(const float4*)(fA + (size_t)ar * DIM + CH + ac * 4);
        int br = i >> 4, bc = i & 15;
        hB[r] = *(const float4*)(fB + (size_t)(CH + br) * NK + bc * 4);
    }

#define COMPUTE_CHUNK()                                                        \
    for (int kq = 0; kq < 4; ++kq) {                                           \
        float4 av = u.st.A[lane * APITCH + wave * 4 + kq];                     \
        ssum += av.x + av.y + av.z + av.w;                                     \
        qsum += av.x*av.x + av.y*av.y + av.z*av.z + av.w*av.w;                 \
        const int kk = wave * 16 + kq * 4;                                     \
        _Pragma("unroll")                                                      \
        for (int c4 = 0; c4 < 16; ++c4) {                                      \
            float4 b0 = u.st.B[(kk+0)*16 + c4];                                \
            float4 b1 = u.st.B[(kk+1)*16 + c4];                                \
            float4 b2 = u.st.B[(kk+2)*16 + c4];                                \
            float4 b3 = u.st.B[(kk+3)*16 + c4];                                \
            acc[c4*4+0] = fmaf(av.w, b3.x, fmaf(av.z, b2.x,                    \
                          fmaf(av.y, b1.x, fmaf(av.x, b0.x, acc[c4*4+0]))));   \
            acc[c4*4+1] = fmaf(av.w, b3.y, fmaf(av.z, b2.y,                    \
                          fmaf(av.y, b1.y, fmaf(av.x, b0.y, acc[c4*4+1]))));   \
            acc[c4*4+2] = fmaf(av.w, b3.z, fmaf(av.z, b2.z,                    \
                          fmaf(av.y, b1.z, fmaf(av.x, b0.z, acc[c4*4+2]))));   \
            acc[c4*4+3] = fmaf(av.w, b3.w, fmaf(av.z, b2.w,                    \
                          fmaf(av.y, b1.w, fmaf(av.x, b0.w, acc[c4*4+3]))));   \
        }                                                                      \
    }

    COMPUTE_CHUNK();          // chunk 0
    __syncthreads();          // all LDS reads of chunk 0 done
    #pragma unroll
    for (int r = 0; r < 4; ++r) {
        int i = t + 512 * r;
        int ar = i >> 5, ac = i & 31;
        u.st.A[ar * APITCH + ac] = hA[r];
        int br = i >> 4, bc = i & 15;
        u.st.B[br * 16 + bc] = hB[r];
    }
    __syncthreads();
    COMPUTE_CHUNK();          // chunk 1
    __syncthreads();          // A/B LDS now dead -> reuse as comb
#undef COMPUTE_CHUNK

    statLDS[wave][lane] = make_float2(ssum, qsum);

    // ---- tree-combine the 8 wave partials into wave 0 (padded, 2-way free)
    if (wave >= 4) {
        float4* dst = &u.comb[(size_t)(wave - 4) * TM * 17 + lane * 17];
        #pragma unroll
        for (int c4 = 0; c4 < 16; ++c4)
            dst[c4] = make_float4(acc[c4*4], acc[c4*4+1], acc[c4*4+2], acc[c4*4+3]);
    }
    __syncthreads();
    if (wave < 4) {
        const float4* src = &u.comb[(size_t)wave * TM * 17 + lane * 17];
        #pragma unroll
        for (int c4 = 0; c4 < 16; ++c4) {
            float4 v = src[c4];
            acc[c4*4]+=v.x; acc[c4*4+1]+=v.y; acc[c4*4+2]+=v.z; acc[c4*4+3]+=v.w;
        }
    }
    __syncthreads();
    if (wave == 2 || wave == 3) {
        float4* dst = &u.comb[(size_t)(wave - 2) * TM * 17 + lane * 17];
        #pragma unroll
        for (int c4 = 0; c4 < 16; ++c4)
            dst[c4] = make_float4(acc[c4*4], acc[c4*4+1], acc[c4*4+2], acc[c4*4+3]);
    }
    __syncthreads();
    if (wave < 2) {
        const float4* src = &u.comb[(size_t)wave * TM * 17 + lane * 17];
        #pragma unroll
        for (int c4 = 0; c4 < 16; ++c4) {
            float4 v = src[c4];
            acc[c4*4]+=v.x; acc[c4*4+1]+=v.y; acc[c4*4+2]+=v.z; acc[c4*4+3]+=v.w;
        }
    }
    __syncthreads();
    if (wave == 1) {
        float4* dst = &u.comb[(size_t)lane * 17];
        #pragma unroll
        for (int c4 = 0; c4 < 16; ++c4)
            dst[c4] = make_float4(acc[c4*4], acc[c4*4+1], acc[c4*4+2], acc[c4*4+3]);
    }
    __syncthreads();
    if (wave == 0) {
        const float4* src = &u.comb[(size_t)lane * 17];
        float* dp = ws + WS_DOTP + ((size_t)tile * 2 + khalf) * TM * NK + lane * NK;
        #pragma unroll
        for (int c4 = 0; c4 < 16; ++c4) {
            float4 v = src[c4];
            *(float4*)(dp + c4 * 4) = make_float4(
                acc[c4*4]+v.x, acc[c4*4+1]+v.y, acc[c4*4+2]+v.z, acc[c4*4+3]+v.w);
        }
        float s = 0.f, q = 0.f;
        #pragma unroll
        for (int w = 0; w < 8; ++w) { float2 v = statLDS[w][lane]; s += v.x; q += v.y; }
        ((float2*)(ws + WS_STATP))[((size_t)tile * 2 + khalf) * TM + lane] =
            make_float2(s, q);
    }
}

// ---------------------------------------------------------------------------
// Epilogue: fuse K-halves, distance, min/argmin (packed-key butterfly),
// centroid override (last-write-wins), energy. 128 blocks x 4 waves;
// wave handles 16 rows; lane = centroid column.
// ---------------------------------------------------------------------------
__global__ __launch_bounds__(256) void epi_kernel(
    const float* __restrict__ ws, const int* __restrict__ cid,
    float* __restrict__ out)
{
    const int lane = threadIdx.x & 63;
    const int wave = threadIdx.x >> 6;
    const int tile = blockIdx.x;

    const float cq  = ws[WS_SQC + lane];
    const float cs  = ws[WS_SC + lane];
    const int   myc = cid[lane];

    const float*  dp0 = ws + WS_DOTP + ((size_t)tile * 2 + 0) * TM * NK;
    const float*  dp1 = ws + WS_DOTP + ((size_t)tile * 2 + 1) * TM * NK;
    const float2* sp0 = (const float2*)(ws + WS_STATP) + (size_t)tile * 2 * TM;
    const float2* sp1 = sp0 + TM;

    float esum = 0.f;
    for (int rr = wave * 16; rr < wave * 16 + 16; ++rr) {
        float dot = dp0[rr * NK + lane] + dp1[rr * NK + lane];
        float2 s0 = sp0[rr], s1 = sp1[rr];
        float qr = s0.y + s1.y, sr = s0.x + s1.x;
        float d2 = qr + cq - 2.f * dot + 2.0e-6f * (sr - cs) + 5.12e-10f;
        float dist = sqrtf(fmaxf(d2, 0.f));
        unsigned long long key =
            (((unsigned long long)__float_as_uint(dist)) << 6) | (unsigned)lane;
        #pragma unroll
        for (int off = 32; off; off >>= 1) {
            unsigned long long o = __shfl_xor(key, off);
            key = (o < key) ? o : key;
        }
        const int gi = tile * TM + rr;
        float y = (float)(unsigned)(key & 63ull);
        unsigned long long ball = __ballot(myc == gi);
        if (ball) y = (float)(63 - __clzll(ball));   // last write wins (max k)
        esum += __uint_as_float((unsigned)(key >> 6));
        if (lane == 0) out[1 + gi] = y;
    }
    if (lane == 0) atomicAdd(out, -esum);
}

extern "C" void kernel_launch(void* const* d_in, const int* in_sizes, int n_in,
                              void* d_out, int out_size, void* d_ws, size_t ws_size,
                              hipStream_t stream) {
    const float* f   = (const float*)d_in[0];
    const int*   cid = (const int*)d_in[1];
    float*       out = (float*)d_out;
    float*       ws  = (float*)d_ws;     // ~4.4 MB used

    prep_kernel<<<NK, 64, 0, stream>>>(f, cid, ws, out);
    gemm_kernel<<<2 * NTILE, 512, 0, stream>>>(f, ws + WS_CTT, ws);
    epi_kernel<<<NTILE, 256, 0, stream>>>(ws, cid, out);
}

// Round 6
// 37.279 us; speedup vs baseline: 1.3048x; 1.3048x over previous
//
#include <hip/hip_runtime.h>

#define NPTS  8192
#define DIM   512
#define NK    64
#define BM    32            // rows per block tile
#define BK    128           // dims per staged chunk
#define NCH   (DIM/BK)      // 4 chunks
#define NTILE (NPTS/BM)     // 256 blocks

// ---------------------------------------------------------------------------
// Prep: gather centroid rows into transposed ctT[d][n] (so fused kernel's B
// staging is a linear copy), per-centroid stats, zero the energy accumulator.
// ---------------------------------------------------------------------------
__global__ __launch_bounds__(64) void prep_kernel(
    const float* __restrict__ f, const int* __restrict__ cid,
    float* __restrict__ ws, float* __restrict__ out)
{
    const int k = blockIdx.x;      // one wave per centroid
    const int lane = threadIdx.x;
    if (k == 0 && lane == 0) out[0] = 0.f;   // stream order: before fused
    float* ctT = ws;
    const float* row = f + (size_t)cid[k] * DIM;
    float4 a = *(const float4*)(row + lane * 8);
    float4 b = *(const float4*)(row + lane * 8 + 4);
    const int d = lane * 8;
    ctT[(d+0)*NK + k] = a.x;  ctT[(d+1)*NK + k] = a.y;
    ctT[(d+2)*NK + k] = a.z;  ctT[(d+3)*NK + k] = a.w;
    ctT[(d+4)*NK + k] = b.x;  ctT[(d+5)*NK + k] = b.y;
    ctT[(d+6)*NK + k] = b.z;  ctT[(d+7)*NK + k] = b.w;
    float s = a.x+a.y+a.z+a.w + b.x+b.y+b.z+b.w;
    float q = a.x*a.x+a.y*a.y+a.z*a.z+a.w*a.w
            + b.x*b.x+b.y*b.y+b.z*b.z+b.w*b.w;
    #pragma unroll
    for (int off = 32; off; off >>= 1) {
        s += __shfl_xor(s, off);
        q += __shfl_xor(q, off);
    }
    if (lane == 0) { ws[DIM*NK + k] = q; ws[DIM*NK + NK + k] = s; }
}

// ---------------------------------------------------------------------------
// Fused GEMM + epilogue. 256 blocks x 512 threads. Block tile 32x64, K=512.
// 8 waves each own a 16-dim slice per 128-dim chunk (64 dims total).
// Thread microtile 4x8: lane -> (rg=lane&7 -> rows rg*4..+4, cg=lane>>3 ->
// cols cg*8..+8). acc[4][8] = 32 VGPRs (R4's acc[64] spilled at VGPR=68 —
// keep microtile register-safe, no min-waves launch_bounds hint).
// A stored k-major in LDS: scalar conflict-free writes, aligned b128 reads.
// Per k-step per thread: 3x ds_read_b128 per 32 FMAs (1.5 B/FMA).
// ---------------------------------------------------------------------------
__global__ __launch_bounds__(512) void fused_kernel(
    const float* __restrict__ f, const int* __restrict__ cid,
    const float* __restrict__ ws, float* __restrict__ out)
{
    __shared__ float Al[BK * BM];        // [k][row] 16 KB
    __shared__ float Bl[BK * NK];        // [k][col] 32 KB
    __shared__ float statS[8][BM], statQ[8][BM];   // 2 KB
    __shared__ float cqL[NK], csL[NK];
    __shared__ int   cidL[NK];

    const int t    = threadIdx.x;
    const int lane = t & 63;
    const int w    = t >> 6;          // wave id = K-slice
    const int rg   = lane & 7;
    const int cg   = lane >> 3;
    const int tile = blockIdx.x;

    const float* ctT = ws;
    const float* sqc = ws + DIM * NK;
    const float* scv = sqc + NK;
    if (t < NK) { cqL[t] = sqc[t]; csL[t] = scv[t]; cidL[t] = cid[t]; }

    // staging roles: A row = t&31 (fixed per thread), k4 = t>>5 and +16.
    const int arow = t & 31;
    const int ak4  = t >> 5;
    const float* fA = f + (size_t)(tile * BM + arow) * DIM;

    float acc[4][8];
    #pragma unroll
    for (int r = 0; r < 4; ++r)
        #pragma unroll
        for (int c = 0; c < 8; ++c) acc[r][c] = 0.f;
    float sp = 0.f, qp = 0.f;

#define STAT4(v) do { sp += v.x+v.y+v.z+v.w; \
                      qp += v.x*v.x+v.y*v.y+v.z*v.z+v.w*v.w; } while (0)
#define AWRITE(k4, v) do { int kk_ = (k4) * 4; \
        Al[(kk_+0)*BM + arow] = v.x; Al[(kk_+1)*BM + arow] = v.y; \
        Al[(kk_+2)*BM + arow] = v.z; Al[(kk_+3)*BM + arow] = v.w; } while (0)

    // ---- stage chunk 0
    {
        float4 a0 = *(const float4*)(fA + ak4 * 4);
        float4 a1 = *(const float4*)(fA + (ak4 + 16) * 4);
        STAT4(a0); STAT4(a1);
        AWRITE(ak4, a0); AWRITE(ak4 + 16, a1);
        #pragma unroll
        for (int j = 0; j < 4; ++j) {
            int i = t + 512 * j;
            *(float4*)&Bl[i * 4] = *(const float4*)(ctT + i * 4);
        }
    }
    __syncthreads();

    for (int c = 0; c < NCH; ++c) {
        float4 pa0, pa1, pb[4];
        if (c + 1 < NCH) {   // T14: issue next-chunk loads before compute
            pa0 = *(const float4*)(fA + (c + 1) * BK + ak4 * 4);
            pa1 = *(const float4*)(fA + (c + 1) * BK + (ak4 + 16) * 4);
            #pragma unroll
            for (int j = 0; j < 4; ++j) {
                int i = t + 512 * j;
                pb[j] = *(const float4*)(ctT + (size_t)(c + 1) * BK * NK + i * 4);
            }
        }
        #pragma unroll 4
        for (int kq = 0; kq < 16; ++kq) {
            const int k = w * 16 + kq;
            float4 av = *(const float4*)&Al[k * BM + rg * 4];
            float4 b0 = *(const float4*)&Bl[k * NK + cg * 8];
            float4 b1 = *(const float4*)&Bl[k * NK + cg * 8 + 4];
            const float a4[4] = {av.x, av.y, av.z, av.w};
            // NOTE: av here multiplies along K? No — av spans 4 ROWS at dim k.
            #pragma unroll
            for (int r = 0; r < 4; ++r) {
                acc[r][0] = fmaf(a4[r], b0.x, acc[r][0]);
                acc[r][1] = fmaf(a4[r], b0.y, acc[r][1]);
                acc[r][2] = fmaf(a4[r], b0.z, acc[r][2]);
                acc[r][3] = fmaf(a4[r], b0.w, acc[r][3]);
                acc[r][4] = fmaf(a4[r], b1.x, acc[r][4]);
                acc[r][5] = fmaf(a4[r], b1.y, acc[r][5]);
                acc[r][6] = fmaf(a4[r], b1.z, acc[r][6]);
                acc[r][7] = fmaf(a4[r], b1.w, acc[r][7]);
            }
        }
        __syncthreads();      // all LDS reads of this chunk done
        if (c + 1 < NCH) {
            STAT4(pa0); STAT4(pa1);
            AWRITE(ak4, pa0); AWRITE(ak4 + 16, pa1);
            #pragma unroll
            for (int j = 0; j < 4; ++j) *(float4*)&Bl[(t + 512 * j) * 4] = pb[j];
        }
        __syncthreads();
    }
#undef AWRITE
#undef STAT4

    // row stats: lanes l and l+32 share row (t&31); combine, store per wave.
    sp += __shfl_xor(sp, 32);
    qp += __shfl_xor(qp, 32);
    if (lane < BM) { statS[w][lane] = sp; statQ[w][lane] = qp; }

    // ---- tree-combine 8 wave partials through dead A/B LDS ----
#define ACC_STORE(base) do { float* d_ = (base) + (size_t)(rg*4)*NK + cg*8;    \
        _Pragma("unroll") for (int r = 0; r < 4; ++r) {                        \
            *(float4*)(d_ + r*NK)     = make_float4(acc[r][0],acc[r][1],acc[r][2],acc[r][3]); \
            *(float4*)(d_ + r*NK + 4) = make_float4(acc[r][4],acc[r][5],acc[r][6],acc[r][7]); } } while (0)
#define ACC_LOAD_ADD(base) do { const float* s_ = (base) + (size_t)(rg*4)*NK + cg*8; \
        _Pragma("unroll") for (int r = 0; r < 4; ++r) {                        \
            float4 v0 = *(const float4*)(s_ + r*NK);                           \
            float4 v1 = *(const float4*)(s_ + r*NK + 4);                       \
            acc[r][0]+=v0.x; acc[r][1]+=v0.y; acc[r][2]+=v0.z; acc[r][3]+=v0.w;\
            acc[r][4]+=v1.x; acc[r][5]+=v1.y; acc[r][6]+=v1.z; acc[r][7]+=v1.w; } } while (0)

    if (w >= 4) ACC_STORE(Bl + (w - 4) * (BM * NK));   // Bl: 4 regions x 2048
    __syncthreads();
    if (w < 4)  ACC_LOAD_ADD(Bl + w * (BM * NK));
    __syncthreads();
    if (w == 2 || w == 3) ACC_STORE(Al + (w - 2) * (BM * NK));  // Al: 2 regions
    __syncthreads();
    if (w < 2)  ACC_LOAD_ADD(Al + w * (BM * NK));
    __syncthreads();
    if (w == 1) ACC_STORE(Bl);
    __syncthreads();
    if (w == 0) {
        ACC_LOAD_ADD(Bl);
#undef ACC_STORE
#undef ACC_LOAD_ADD
        // ---- epilogue (wave 0 only): distance, argmin, override, energy ----
        float esum = 0.f;
        #pragma unroll
        for (int r = 0; r < 4; ++r) {
            const int row = rg * 4 + r;
            float s = 0.f, q = 0.f;
            #pragma unroll
            for (int w8 = 0; w8 < 8; ++w8) { s += statS[w8][row]; q += statQ[w8][row]; }
            unsigned long long key = ~0ull;
            #pragma unroll
            for (int cc = 0; cc < 8; ++cc) {
                const int col = cg * 8 + cc;
                float d2 = q + cqL[col] - 2.f * acc[r][cc]
                         + 2.0e-6f * (s - csL[col]) + 5.12e-10f;
                float dist = sqrtf(fmaxf(d2, 0.f));
                unsigned long long kk =
                    (((unsigned long long)__float_as_uint(dist)) << 6) | (unsigned)col;
                key = (kk < key) ? kk : key;
            }
            key = min(key, __shfl_xor(key, 8));
            key = min(key, __shfl_xor(key, 16));
            key = min(key, __shfl_xor(key, 32));
            if (cg == 0) {
                const int gi = tile * BM + row;
                float y = (float)(unsigned)(key & 63ull);
                for (int k = 0; k < NK; ++k)          // last write wins
                    if (cidL[k] == gi) y = (float)k;
                out[1 + gi] = y;
                esum += __uint_as_float((unsigned)(key >> 6));
            }
        }
        esum += __shfl_xor(esum, 1);
        esum += __shfl_xor(esum, 2);
        esum += __shfl_xor(esum, 4);
        if (lane == 0) atomicAdd(out, -esum);
    }
}

extern "C" void kernel_launch(void* const* d_in, const int* in_sizes, int n_in,
                              void* d_out, int out_size, void* d_ws, size_t ws_size,
                              hipStream_t stream) {
    const float* f   = (const float*)d_in[0];
    const int*   cid = (const int*)d_in[1];
    float*       out = (float*)d_out;
    float*       ws  = (float*)d_ws;     // ctT 128KB + sqc/sc 512B

    prep_kernel<<<NK, 64, 0, stream>>>(f, cid, ws, out);
    fused_kernel<<<NTILE, 512, 0, stream>>>(f, cid, ws, out);
}